// Round 1
// baseline (135.486 us; speedup 1.0000x reference)
//
#include <hip/hip_runtime.h>
#include <hip/hip_bf16.h>
#include <math.h>

// Problem constants: B=32, T=2048, J=64, D=256 (fp32 in/out)
#define BQ 32
#define TQ 2048
#define JQ 64
#define DQ 256

// ---------------------------------------------------------------------------
// Kernel 1: z1[b,t] = max_j s[b,t,j].  One float4 per thread; rows are 16
// float4s, so 16 consecutive lanes share one row -> shfl_xor max over 16.
// ---------------------------------------------------------------------------
__global__ __launch_bounds__(256) void k_rowmax(const float4* __restrict__ s4,
                                                float* __restrict__ z1) {
    int idx = blockIdx.x * 256 + threadIdx.x;      // float4 index
    float4 v = s4[idx];
    float m = fmaxf(fmaxf(v.x, v.y), fmaxf(v.z, v.w));
    #pragma unroll
    for (int off = 1; off < 16; off <<= 1)
        m = fmaxf(m, __shfl_xor(m, off));
    if ((threadIdx.x & 15) == 0)
        z1[idx >> 4] = m;
}

// ---------------------------------------------------------------------------
// Kernel 2: per-batch softmax over T. One block per b (256 thr, 8 vals each).
// Writes normalized weights w[b,t] and zeroes pooled[b,:] (ws is poisoned).
// ---------------------------------------------------------------------------
__global__ __launch_bounds__(256) void k_softmax(const float* __restrict__ z1,
                                                 float* __restrict__ w,
                                                 float* __restrict__ pooled) {
    int b = blockIdx.x;
    int tid = threadIdx.x;
    __shared__ float lds[256];

    const float* zr = z1 + b * TQ;
    float zv[8];
    float m = -INFINITY;
    #pragma unroll
    for (int i = 0; i < 8; ++i) {
        zv[i] = zr[tid + i * 256];
        m = fmaxf(m, zv[i]);
    }
    lds[tid] = m;
    __syncthreads();
    for (int s = 128; s > 0; s >>= 1) {
        if (tid < s) lds[tid] = fmaxf(lds[tid], lds[tid + s]);
        __syncthreads();
    }
    m = lds[0];
    __syncthreads();

    float sum = 0.f;
    #pragma unroll
    for (int i = 0; i < 8; ++i) {
        zv[i] = expf(zv[i] - m);
        sum += zv[i];
    }
    lds[tid] = sum;
    __syncthreads();
    for (int s = 128; s > 0; s >>= 1) {
        if (tid < s) lds[tid] += lds[tid + s];
        __syncthreads();
    }
    float invZ = 1.0f / lds[0];

    #pragma unroll
    for (int i = 0; i < 8; ++i)
        w[b * TQ + tid + i * 256] = zv[i] * invZ;

    pooled[b * DQ + tid] = 0.f;   // init accumulator for kernel 3
}

// ---------------------------------------------------------------------------
// Kernel 3: pooled[b,d] += sum over a 64-t chunk of w[b,t]*h[b,t,d].
// grid = B*32 blocks; thread = (t_sub 0..3) x (d4 0..63), float4 h loads
// (1 KiB per wave instruction). LDS-reduce across t_sub, 256 atomics/block.
// ---------------------------------------------------------------------------
__global__ __launch_bounds__(256) void k_pool(const float4* __restrict__ h4,
                                              const float* __restrict__ w,
                                              float* __restrict__ pooled) {
    int b = blockIdx.x >> 5;
    int chunk = blockIdx.x & 31;
    int tid = threadIdx.x;
    int t_sub = tid >> 6;          // 0..3
    int d4 = tid & 63;             // 0..63
    int t0 = chunk * 64;
    const float* wr = w + b * TQ;

    float4 acc = make_float4(0.f, 0.f, 0.f, 0.f);
    #pragma unroll
    for (int i = 0; i < 16; ++i) {
        int t = t0 + i * 4 + t_sub;
        float wt = wr[t];                                   // wave-broadcast
        float4 hv = h4[(size_t)(b * TQ + t) * (DQ / 4) + d4];
        acc.x += wt * hv.x;
        acc.y += wt * hv.y;
        acc.z += wt * hv.z;
        acc.w += wt * hv.w;
    }

    __shared__ float sred[256][4];
    sred[tid][0] = acc.x;
    sred[tid][1] = acc.y;
    sred[tid][2] = acc.z;
    sred[tid][3] = acc.w;
    __syncthreads();

    int d = tid;                   // 0..255
    int dd4 = d >> 2;
    int c = d & 3;
    float sum = sred[dd4][c] + sred[64 + dd4][c] +
                sred[128 + dd4][c] + sred[192 + dd4][c];
    atomicAdd(&pooled[b * DQ + d], sum);
}

// ---------------------------------------------------------------------------
// Kernel 4: out[b,t,d] = pooled[b,d], float4 stores. pooled (32 KiB) caches.
// ---------------------------------------------------------------------------
__global__ __launch_bounds__(256) void k_bcast(const float4* __restrict__ pooled4,
                                               float4* __restrict__ out4) {
    int i0 = blockIdx.x * 256 + threadIdx.x;
    #pragma unroll
    for (int k = 0; k < 4; ++k) {
        int i = i0 + k * (4096 * 256);
        int b = i >> 17;           // T*D/4 = 131072 float4 per batch
        int d4 = i & 63;
        out4[i] = pooled4[b * (DQ / 4) + d4];
    }
}

extern "C" void kernel_launch(void* const* d_in, const int* in_sizes, int n_in,
                              void* d_out, int out_size, void* d_ws, size_t ws_size,
                              hipStream_t stream) {
    const float* h = (const float*)d_in[0];   // [B,T,D]
    const float* s = (const float*)d_in[1];   // [B,T,J]
    float* out = (float*)d_out;               // [B,T,D]

    float* ws = (float*)d_ws;
    float* z1 = ws;                      // B*T      = 65536
    float* w = ws + BQ * TQ;             // B*T      = 65536
    float* pooled = ws + 2 * BQ * TQ;    // B*D      = 8192 (16B-aligned)

    // K1: B*T*J/4 = 1,048,576 float4 -> 4096 blocks
    k_rowmax<<<4096, 256, 0, stream>>>((const float4*)s, z1);
    // K2: one block per batch
    k_softmax<<<BQ, 256, 0, stream>>>(z1, w, pooled);
    // K3: 32 chunks of 64 t-rows per batch
    k_pool<<<BQ * 32, 256, 0, stream>>>((const float4*)h, w, pooled);
    // K4: B*T*D/4 = 4,194,304 float4, 4 per thread
    k_bcast<<<4096, 256, 0, stream>>>((const float4*)pooled, (float4*)out);
}

// Round 3
// 131.659 us; speedup vs baseline: 1.0291x; 1.0291x over previous
//
#include <hip/hip_runtime.h>
#include <math.h>

// Problem constants: B=32, T=2048, J=64, D=256 (fp32 in/out)
#define BQ 32
#define TQ 2048
#define JQ 64
#define DQ 256
#define NBLK 1024   // 32 chunks of 64 t-rows per batch; block <-> (b, chunk)
#define NTHR 256

// ws layout (floats): dpart[NBLK] | e[B*T] | ppart[NBLK*DQ]
// Every ws location is written before it is read (poison-safe, no memset).
// Cross-kernel visibility comes from kernel-launch boundaries (coherent),
// NOT grid.sync — R2 showed grid.sync leaves stale per-XCD L2 lines.

// ---------------------------------------------------------------------------
// K1: e[b,t] = exp(max_j s[b,t,j]); dpart[blk] = sum of this chunk's 64 e's.
// One float4/thread; a row is 16 float4s -> 16-lane shfl-xor max.
// ---------------------------------------------------------------------------
__global__ __launch_bounds__(NTHR) void k_rowmax_exp(
    const float4* __restrict__ s4, float* __restrict__ e,
    float* __restrict__ dpart)
{
    const int blk = blockIdx.x, tid = threadIdx.x;
    __shared__ float e_lds[64];

    #pragma unroll
    for (int p = 0; p < 4; ++p) {
        int idx = blk * 1024 + p * 256 + tid;         // float4 index into s
        float4 v = s4[idx];
        float m = fmaxf(fmaxf(v.x, v.y), fmaxf(v.z, v.w));
        m = fmaxf(m, __shfl_xor(m, 1));
        m = fmaxf(m, __shfl_xor(m, 2));
        m = fmaxf(m, __shfl_xor(m, 4));
        m = fmaxf(m, __shfl_xor(m, 8));
        if ((tid & 15) == 0)
            e_lds[p * 16 + (tid >> 4)] = expf(m);     // z1 <= ~5.5, exp safe fp32
    }
    __syncthreads();
    if (tid < 64) {                                   // one full wave
        float v = e_lds[tid];
        e[blk * 64 + tid] = v;
        #pragma unroll
        for (int off = 32; off > 0; off >>= 1)
            v += __shfl_xor(v, off);
        if (tid == 0) dpart[blk] = v;
    }
}

// ---------------------------------------------------------------------------
// K2: ppart[blk, d] = sum_{t in chunk} softmax_w[b,t] * h[b,t,d].
// Each block: den = sum of 32 dpart (L2 broadcast), then float4 h loads
// (each wave reads one full 1 KiB row), LDS-reduce over the 4 t_sub waves.
// ---------------------------------------------------------------------------
__global__ __launch_bounds__(NTHR) void k_pool(
    const float4* __restrict__ h4, const float* __restrict__ e,
    const float* __restrict__ dpart, float* __restrict__ ppart)
{
    const int blk = blockIdx.x, tid = threadIdx.x;
    const int b = blk >> 5;

    float den = 0.f;
    #pragma unroll
    for (int c = 0; c < 32; ++c)                      // L2-hot broadcast loads
        den += dpart[b * 32 + c];
    const float inv = 1.0f / den;

    __shared__ float w_lds[64];
    if (tid < 64) w_lds[tid] = e[blk * 64 + tid] * inv;
    __syncthreads();

    const int t_sub = tid >> 6;                       // 0..3 (wave id)
    const int d4 = tid & 63;                          // 0..63
    const int t0 = (blk & 31) * 64;
    float4 acc = make_float4(0.f, 0.f, 0.f, 0.f);
    #pragma unroll
    for (int i = 0; i < 16; ++i) {
        int tl = i * 4 + t_sub;
        float wt = w_lds[tl];
        float4 hv = h4[(size_t)(b * TQ + t0 + tl) * (DQ / 4) + d4];
        acc.x += wt * hv.x;
        acc.y += wt * hv.y;
        acc.z += wt * hv.z;
        acc.w += wt * hv.w;
    }

    __shared__ float sred[NTHR][4];
    sred[tid][0] = acc.x; sred[tid][1] = acc.y;
    sred[tid][2] = acc.z; sred[tid][3] = acc.w;
    __syncthreads();
    int dd4 = tid >> 2, c4 = tid & 3;                 // tid <-> d in [0,256)
    float sum = sred[dd4][c4] + sred[64 + dd4][c4] +
                sred[128 + dd4][c4] + sred[192 + dd4][c4];
    ppart[blk * DQ + tid] = sum;                      // deterministic, no atomics
}

// ---------------------------------------------------------------------------
// K3: pooled[b,:] = sum of the batch's 32 ppart slices (redundant per block,
// ~32 KiB L2-hot), then broadcast to this block's 64-t slice of out.
// ---------------------------------------------------------------------------
__global__ __launch_bounds__(NTHR) void k_reduce_bcast(
    const float* __restrict__ ppart, float4* __restrict__ out4)
{
    const int blk = blockIdx.x, tid = threadIdx.x;
    const int b = blk >> 5;
    __shared__ __align__(16) float pooled[DQ];

    float p = 0.f;
    #pragma unroll
    for (int c = 0; c < 32; ++c)
        p += ppart[(b * 32 + c) * DQ + tid];
    pooled[tid] = p;
    __syncthreads();

    float4 pv = ((const float4*)pooled)[tid & 63];
    size_t base = (size_t)blk * 4096;                 // 4096 float4 of out/block
    #pragma unroll
    for (int k = 0; k < 16; ++k)
        out4[base + k * 256 + tid] = pv;              // coalesced 16B stores
}

extern "C" void kernel_launch(void* const* d_in, const int* in_sizes, int n_in,
                              void* d_out, int out_size, void* d_ws, size_t ws_size,
                              hipStream_t stream) {
    const float4* h4 = (const float4*)d_in[0];   // [B,T,D]
    const float4* s4 = (const float4*)d_in[1];   // [B,T,J]
    float4* out4 = (float4*)d_out;               // [B,T,D]

    float* ws = (float*)d_ws;
    float* dpart = ws;                           // NBLK
    float* e = ws + NBLK;                        // B*T = 65536
    float* ppart = ws + NBLK + BQ * TQ;          // NBLK*DQ = 262144

    k_rowmax_exp<<<NBLK, NTHR, 0, stream>>>(s4, e, dpart);
    k_pool<<<NBLK, NTHR, 0, stream>>>(h4, e, dpart, ppart);
    k_reduce_bcast<<<NBLK, NTHR, 0, stream>>>(ppart, out4);
}

// Round 4
// 128.622 us; speedup vs baseline: 1.0534x; 1.0236x over previous
//
#include <hip/hip_runtime.h>
#include <math.h>

// Problem constants: B=32, T=2048, J=64, D=256 (fp32 in/out)
#define BQ 32
#define TQ 2048
#define JQ 64
#define DQ 256
#define NBLK 1024   // 32 chunks of 64 t-rows per batch; block <-> (b, chunk)
#define NTHR 256

// Key identity: pooled[b,:] = (sum_t e[b,t]*h[b,t,:]) / (sum_t e[b,t]) with
// e = exp(max_j s) — softmax normalization deferred to K2. This fuses the
// whole s-read AND h-read into one kernel with no e[B,T] global round-trip.
//
// ws layout (floats): dpart[NBLK] | ppart[NBLK*DQ]. Every ws location is
// written before read (poison-safe). Cross-kernel visibility via the kernel
// boundary (R2 showed grid.sync leaves stale per-XCD L2).

// ---------------------------------------------------------------------------
// K1: per 64-t chunk: e_t = exp(max_j s), dpart[blk] = sum e_t,
//     ppart[blk,d] = sum_t e_t * h[b,t,d]   (unnormalized).
// ---------------------------------------------------------------------------
__global__ __launch_bounds__(NTHR) void k_fused_pool(
    const float4* __restrict__ s4, const float4* __restrict__ h4,
    float* __restrict__ dpart, float* __restrict__ ppart)
{
    const int blk = blockIdx.x, tid = threadIdx.x;
    const int b = blk >> 5;
    __shared__ float e_lds[64];

    // --- rowmax + exp over this chunk's 64 rows of s (1024 float4) ---
    #pragma unroll
    for (int p = 0; p < 4; ++p) {
        int idx = blk * 1024 + p * 256 + tid;         // float4 index into s
        float4 v = s4[idx];
        float m = fmaxf(fmaxf(v.x, v.y), fmaxf(v.z, v.w));
        m = fmaxf(m, __shfl_xor(m, 1));
        m = fmaxf(m, __shfl_xor(m, 2));
        m = fmaxf(m, __shfl_xor(m, 4));
        m = fmaxf(m, __shfl_xor(m, 8));
        if ((tid & 15) == 0)
            e_lds[p * 16 + (tid >> 4)] = expf(m);     // z1 <= ~5.5, exp safe fp32
    }
    __syncthreads();

    if (tid < 64) {                                   // one full wave
        float v = e_lds[tid];
        #pragma unroll
        for (int off = 32; off > 0; off >>= 1)
            v += __shfl_xor(v, off);
        if (tid == 0) dpart[blk] = v;                 // partial denominator
    }

    // --- unnormalized weighted pool over the chunk's 64 h-rows ---
    const int t_sub = tid >> 6;                       // wave id 0..3
    const int d4 = tid & 63;                          // float4 lane in D
    const int t0 = (blk & 31) * 64;
    float4 acc = make_float4(0.f, 0.f, 0.f, 0.f);
    #pragma unroll
    for (int i = 0; i < 16; ++i) {
        int tl = i * 4 + t_sub;
        float wt = e_lds[tl];                         // LDS broadcast (free)
        float4 hv = h4[(size_t)(b * TQ + t0 + tl) * (DQ / 4) + d4];
        acc.x += wt * hv.x;
        acc.y += wt * hv.y;
        acc.z += wt * hv.z;
        acc.w += wt * hv.w;
    }

    __shared__ float sred[NTHR][4];
    sred[tid][0] = acc.x; sred[tid][1] = acc.y;
    sred[tid][2] = acc.z; sred[tid][3] = acc.w;
    __syncthreads();
    int dd4 = tid >> 2, c4 = tid & 3;                 // tid <-> d in [0,256)
    float sum = sred[dd4][c4] + sred[64 + dd4][c4] +
                sred[128 + dd4][c4] + sred[192 + dd4][c4];
    ppart[blk * DQ + tid] = sum;                      // deterministic, no atomics
}

// ---------------------------------------------------------------------------
// K2: pooled[b,:] = (sum of batch's 32 ppart slices) / (sum of 32 dpart),
// redundantly per block (L2-hot, ~33 KiB), then broadcast to the block's
// 64-t slice of out with coalesced float4 stores.
// ---------------------------------------------------------------------------
__global__ __launch_bounds__(NTHR) void k_reduce_bcast(
    const float* __restrict__ dpart, const float* __restrict__ ppart,
    float4* __restrict__ out4)
{
    const int blk = blockIdx.x, tid = threadIdx.x;
    const int b = blk >> 5;
    __shared__ __align__(16) float pooled[DQ];

    float den = 0.f;
    #pragma unroll
    for (int c = 0; c < 32; ++c)                      // L2-hot broadcast loads
        den += dpart[b * 32 + c];
    const float inv = 1.0f / den;

    float p = 0.f;
    #pragma unroll
    for (int c = 0; c < 32; ++c)
        p += ppart[(b * 32 + c) * DQ + tid];
    pooled[tid] = p * inv;
    __syncthreads();

    float4 pv = ((const float4*)pooled)[tid & 63];
    size_t base = (size_t)blk * 4096;                 // 4096 float4 of out/block
    #pragma unroll
    for (int k = 0; k < 16; ++k)
        out4[base + k * 256 + tid] = pv;              // coalesced 16B stores
}

extern "C" void kernel_launch(void* const* d_in, const int* in_sizes, int n_in,
                              void* d_out, int out_size, void* d_ws, size_t ws_size,
                              hipStream_t stream) {
    const float4* h4 = (const float4*)d_in[0];   // [B,T,D]
    const float4* s4 = (const float4*)d_in[1];   // [B,T,J]
    float4* out4 = (float4*)d_out;               // [B,T,D]

    float* ws = (float*)d_ws;
    float* dpart = ws;                           // NBLK floats
    float* ppart = ws + NBLK;                    // NBLK*DQ floats

    k_fused_pool<<<NBLK, NTHR, 0, stream>>>(s4, h4, dpart, ppart);
    k_reduce_bcast<<<NBLK, NTHR, 0, stream>>>(dpart, ppart, out4);
}

// Round 5
// 127.982 us; speedup vs baseline: 1.0586x; 1.0050x over previous
//
#include <hip/hip_runtime.h>
#include <math.h>

// Problem constants: B=32, T=2048, J=64, D=256 (fp32 in/out)
#define BQ 32
#define TQ 2048
#define JQ 64
#define DQ 256
#define NBLK1 2048  // K1: 64 chunks of 32 t-rows per batch
#define NBLK2 1024  // K2: 32 chunks of 64 t-rows per batch (write stream)
#define NTHR 256

typedef float f4 __attribute__((ext_vector_type(4)));  // native vec for nt ld/st

// pooled[b,:] = (sum_t e_t*h_t) / (sum_t e_t), e = exp(max_j s); normalization
// deferred to K2. ws: dpart[NBLK1] | ppart[NBLK1*DQ] — all written before read
// (poison-safe). Cross-kernel visibility via the kernel boundary (R2: grid.sync
// leaves stale per-XCD L2).

// ---------------------------------------------------------------------------
// K1: per 32-t chunk: e_t = exp(max_j s), dpart[blk] = sum e_t,
//     ppart[blk,d] = sum_t e_t * h[b,t,d]  (unnormalized).
// 2048 blocks -> 8 blocks/CU of streaming waves; nt loads (no reuse).
// ---------------------------------------------------------------------------
__global__ __launch_bounds__(NTHR) void k_fused_pool(
    const f4* __restrict__ s4, const f4* __restrict__ h4,
    float* __restrict__ dpart, float* __restrict__ ppart)
{
    const int blk = blockIdx.x, tid = threadIdx.x;
    const int b = blk >> 6;                           // 64 chunks per batch
    const int t0 = (blk & 63) * 32;
    __shared__ float e_lds[32];

    // --- rowmax + exp over this chunk's 32 rows of s (512 f4) ---
    #pragma unroll
    for (int p = 0; p < 2; ++p) {
        int idx = blk * 512 + p * 256 + tid;          // f4 index into s
        f4 v = __builtin_nontemporal_load(&s4[idx]);
        float m = fmaxf(fmaxf(v.x, v.y), fmaxf(v.z, v.w));
        m = fmaxf(m, __shfl_xor(m, 1));
        m = fmaxf(m, __shfl_xor(m, 2));
        m = fmaxf(m, __shfl_xor(m, 4));
        m = fmaxf(m, __shfl_xor(m, 8));
        if ((tid & 15) == 0)
            e_lds[p * 16 + (tid >> 4)] = expf(m);     // z1 <= ~5.5, fp32-safe
    }
    __syncthreads();

    if (tid < 32) {                                   // lanes 0..31 of wave 0
        float v = e_lds[tid];
        v += __shfl_xor(v, 16);
        v += __shfl_xor(v, 8);
        v += __shfl_xor(v, 4);
        v += __shfl_xor(v, 2);
        v += __shfl_xor(v, 1);
        if (tid == 0) dpart[blk] = v;                 // partial denominator
    }

    // --- unnormalized weighted pool over the chunk's 32 h-rows ---
    const int t_sub = tid >> 6;                       // wave id 0..3
    const int d4 = tid & 63;                          // f4 lane in D
    f4 acc = (f4)(0.f);
    #pragma unroll
    for (int i = 0; i < 8; ++i) {
        int tl = i * 4 + t_sub;                       // 0..31
        float wt = e_lds[tl];                         // LDS broadcast
        f4 hv = __builtin_nontemporal_load(
            &h4[(size_t)(b * TQ + t0 + tl) * (DQ / 4) + d4]);
        acc += wt * hv;
    }

    __shared__ float sred[NTHR][4];
    sred[tid][0] = acc.x; sred[tid][1] = acc.y;
    sred[tid][2] = acc.z; sred[tid][3] = acc.w;
    __syncthreads();
    int dd4 = tid >> 2, c4 = tid & 3;                 // tid <-> d in [0,256)
    float sum = sred[dd4][c4] + sred[64 + dd4][c4] +
                sred[128 + dd4][c4] + sred[192 + dd4][c4];
    ppart[blk * DQ + tid] = sum;                      // deterministic, no atomics
}

// ---------------------------------------------------------------------------
// K2: pooled[b,:] = (sum of batch's 64 ppart slices) / (sum of 64 dpart),
// redundantly per block (L2/L3-hot, ~65 KiB), then broadcast to the block's
// 64-t slice of out with coalesced nontemporal f4 stores.
// ---------------------------------------------------------------------------
__global__ __launch_bounds__(NTHR) void k_reduce_bcast(
    const float* __restrict__ dpart, const float* __restrict__ ppart,
    f4* __restrict__ out4)
{
    const int blk = blockIdx.x, tid = threadIdx.x;
    const int b = blk >> 5;                           // 32 out-chunks per batch
    __shared__ __align__(16) float pooled[DQ];

    float den = 0.f;
    #pragma unroll
    for (int c = 0; c < 64; ++c)                      // broadcast loads
        den += dpart[b * 64 + c];
    const float inv = 1.0f / den;

    float p = 0.f;
    #pragma unroll
    for (int c = 0; c < 64; ++c)                      // coalesced, cache-hot
        p += ppart[(b * 64 + c) * DQ + tid];
    pooled[tid] = p * inv;
    __syncthreads();

    f4 pv = ((const f4*)pooled)[tid & 63];
    size_t base = (size_t)blk * 4096;                 // 4096 f4 of out/block
    #pragma unroll
    for (int k = 0; k < 16; ++k)
        __builtin_nontemporal_store(pv, &out4[base + k * 256 + tid]);
}

extern "C" void kernel_launch(void* const* d_in, const int* in_sizes, int n_in,
                              void* d_out, int out_size, void* d_ws, size_t ws_size,
                              hipStream_t stream) {
    const f4* h4 = (const f4*)d_in[0];           // [B,T,D]
    const f4* s4 = (const f4*)d_in[1];           // [B,T,J]
    f4* out4 = (f4*)d_out;                       // [B,T,D]

    float* ws = (float*)d_ws;
    float* dpart = ws;                           // NBLK1 floats
    float* ppart = ws + NBLK1;                   // NBLK1*DQ floats (2 MiB)

    k_fused_pool<<<NBLK1, NTHR, 0, stream>>>(s4, h4, dpart, ppart);
    k_reduce_bcast<<<NBLK2, NTHR, 0, stream>>>(dpart, ppart, out4);
}